// Round 26
// baseline (88.337 us; speedup 1.0000x reference)
//
#include <hip/hip_runtime.h>

#define NEMB 512
#define DIM 64
#define NB 32
#define HW 4096
#define NTOK (NB * HW)            // 131072
#define TPB 512                   // 8 waves
#define TOKBLK 512                // tokens per block
#define BLOCKS (NTOK / TOKBLK)    // 256

typedef float f32x16 __attribute__((ext_vector_type(16)));
typedef short bf16x8 __attribute__((ext_vector_type(8)));

// ws float-offsets
#define WS_PART 0                 // [512] loss partials
#define WS_SUMC 512               // [512] exact row norms
#define WS_CMAXP 1024             // [8] per-prep-block cmax partials
#define WS_SCMAXP 1032            // [8] per-prep-block scmax partials
#define WS_CH 1040                // u32[512*32] packed bf16-hi (16B aligned)
#define WS_CL (1040 + 16384)      // u32[512*32] packed bf16-lo
#define WS_CNT (1040 + 32768)     // [1] int: blocks-done counter

// RNE float->bf16 (self-contained, deterministic; inputs finite)
__device__ __forceinline__ unsigned short f2bf(float f) {
    unsigned u = __float_as_uint(f);
    unsigned r = u + 0x7FFFu + ((u >> 16) & 1u);
    return (unsigned short)(r >> 16);
}
__device__ __forceinline__ float bf2f(unsigned short h) {
    return __uint_as_float((unsigned)h << 16);
}

// prep: PARALLEL (8 blocks x 64). Row k: exact sumc (R2 order) + bf16 hi/lo
// split (packed) + per-block cmax/scmax partials. Block 0 also zeroes the
// done-counter (deterministic per call; graph-replay safe).
__global__ void vq_prep(const float* __restrict__ cb, float* __restrict__ ws)
{
    const int tid = threadIdx.x;              // 0..63 (one wave)
    const int k   = blockIdx.x * 64 + tid;    // 0..511

    if (blockIdx.x == 0 && tid == 0)
        *(int*)(ws + WS_CNT) = 0;

    float sc_v;
    {   // exact sumc: rounded squares, sequential adds (bit-exact R2)
#pragma clang fp contract(off)
        float s = 0.f;
#pragma unroll
        for (int d = 0; d < DIM; ++d) {
            float v = cb[k * DIM + d];
            float p = v * v;
            s = s + p;
        }
        sc_v = s;
        ws[WS_SUMC + k] = s;
    }

    float cmax_t = 0.f;
    unsigned* chp = (unsigned*)(ws + WS_CH) + k * 32;
    unsigned* clp = (unsigned*)(ws + WS_CL) + k * 32;
#pragma unroll
    for (int q = 0; q < 32; ++q) {
        float v0 = cb[k * DIM + 2 * q], v1 = cb[k * DIM + 2 * q + 1];
        cmax_t = fmaxf(cmax_t, fmaxf(fabsf(v0), fabsf(v1)));
        unsigned short h0 = f2bf(v0), h1 = f2bf(v1);
        unsigned short l0 = f2bf(v0 - bf2f(h0)), l1 = f2bf(v1 - bf2f(h1));
        chp[q] = (unsigned)h0 | ((unsigned)h1 << 16);
        clp[q] = (unsigned)l0 | ((unsigned)l1 << 16);
    }

    // wave-wide fmax reduce (order-independent => deterministic)
    float cm = cmax_t, sm = sc_v;
#pragma unroll
    for (int off = 32; off; off >>= 1) {
        cm = fmaxf(cm, __shfl_xor(cm, off));
        sm = fmaxf(sm, __shfl_xor(sm, off));
    }
    if (tid == 0) {
        ws[WS_CMAXP  + blockIdx.x] = cm;
        ws[WS_SCMAXP + blockIdx.x] = sm;
    }
}

// main: MFMA bf16-split filter (A=codes, B=tokens) + exact fp32 re-rank.
// == R25's measured-83us kernel + fused last-block loss-final reduce.
__global__ __launch_bounds__(TPB, 2)
void vq_main(const float* __restrict__ z_e, const float* __restrict__ cb,
             float* __restrict__ ws, float* __restrict__ out,
             float* __restrict__ loss_part, float* __restrict__ inds_out,
             float* __restrict__ loss_out)
{
    __shared__ uint4 ch_s[NEMB * 9];   // 72 KB, rotation-swizzled blocks
    __shared__ uint4 cl_s[NEMB * 9];   // 72 KB
    __shared__ float sumc_s[NEMB];     // 2 KB
    __shared__ float red_s[TPB];       // 2 KB
    __shared__ float sc2[2];
    __shared__ int   last_s;

    const int tid  = threadIdx.x;
    const int gid  = blockIdx.x;
    const int b    = gid >> 3;
    const int base = (gid & 7) * TOKBLK;
    const int w    = tid >> 6;
    const int l    = tid & 63;
    const int col  = l & 31;
    const int half = l >> 5;

    // ---- stage swizzled bf16 codebook + sumc ----
    {
        const uint4* chg = (const uint4*)(ws + WS_CH);
        const uint4* clg = (const uint4*)(ws + WS_CL);
#pragma unroll
        for (int i = 0; i < 8; ++i) {
            int idx = i * TPB + tid;          // 0..4095
            int c = idx >> 3, bd = idx & 7;
            int slot = (bd + c) & 7;          // rotation swizzle (~2-way banks)
            ch_s[c * 9 + slot] = chg[idx];
            cl_s[c * 9 + slot] = clg[idx];
        }
        sumc_s[tid] = ws[WS_SUMC + tid];
        if (tid == 0) {
            float cm = ws[WS_CMAXP], sm = ws[WS_SCMAXP];
#pragma unroll
            for (int i = 1; i < 8; ++i) {
                cm = fmaxf(cm, ws[WS_CMAXP + i]);
                sm = fmaxf(sm, ws[WS_SCMAXP + i]);
            }
            sc2[0] = cm; sc2[1] = sm;
        }
    }

    // ---- z B-frags (bf16 hi/lo) + L1z / approx sumz ----
    const float* zb = z_e + (size_t)b * DIM * HW;
    const int t0 = base + w * 64;
    uint4 bzh[2][4], bzl[2][4];
    float l1p[2] = {0.f, 0.f}, szp[2] = {0.f, 0.f};
#pragma unroll
    for (int tt = 0; tt < 2; ++tt) {
        int tok = t0 + tt * 32 + col;
#pragma unroll
        for (int ks = 0; ks < 4; ++ks) {
            unsigned hh[8], ll[8];
#pragma unroll
            for (int j = 0; j < 8; ++j) {
                int d = 16 * ks + 8 * half + j;
                float v = zb[(size_t)d * HW + tok];
                l1p[tt] += fabsf(v);
                szp[tt] = fmaf(v, v, szp[tt]);
                unsigned short h = f2bf(v);
                unsigned short lo = f2bf(v - bf2f(h));
                hh[j] = h; ll[j] = lo;
            }
            bzh[tt][ks] = make_uint4(hh[0] | (hh[1] << 16), hh[2] | (hh[3] << 16),
                                     hh[4] | (hh[5] << 16), hh[6] | (hh[7] << 16));
            bzl[tt][ks] = make_uint4(ll[0] | (ll[1] << 16), ll[2] | (ll[3] << 16),
                                     ll[4] | (ll[5] << 16), ll[6] | (ll[7] << 16));
        }
    }
    float L1[2], SZ[2];
#pragma unroll
    for (int tt = 0; tt < 2; ++tt) {
        L1[tt] = l1p[tt] + __shfl_xor(l1p[tt], 32);
        SZ[tt] = szp[tt] + __shfl_xor(szp[tt], 32);
    }
    __syncthreads();

    const float cmax = sc2[0], scmax = sc2[1];
    float gapd[2];
#pragma unroll
    for (int tt = 0; tt < 2; ++tt)
        gapd[tt] = 1.2e-4f * cmax * L1[tt] + 0.5f * scmax + 1.2e-7f * SZ[tt] + 1e-6f;

    // ---- MFMA filter: D[code][token], 3 split passes ----
    unsigned mask0[8], mask1[8];
#pragma unroll
    for (int i = 0; i < 8; ++i) { mask0[i] = 0u; mask1[i] = 0u; }
    float runm[2] = {-3.402823466e38f, -3.402823466e38f};

    for (int ct = 0; ct < 16; ++ct) {
        bf16x8 ah[4], al[4];
        const int c = 32 * ct + col;
        const int rowb = c * 9;
#pragma unroll
        for (int ks = 0; ks < 4; ++ks) {
            int slot = ((2 * ks + half) + c) & 7;
            uint4 u1 = ch_s[rowb + slot];
            uint4 u2 = cl_s[rowb + slot];
            ah[ks] = *(bf16x8*)&u1;
            al[ks] = *(bf16x8*)&u2;
        }
#pragma unroll
        for (int tt = 0; tt < 2; ++tt) {
            f32x16 acc = {0.f, 0.f, 0.f, 0.f, 0.f, 0.f, 0.f, 0.f,
                          0.f, 0.f, 0.f, 0.f, 0.f, 0.f, 0.f, 0.f};
#pragma unroll
            for (int ks = 0; ks < 4; ++ks)
                acc = __builtin_amdgcn_mfma_f32_32x32x16_bf16(ah[ks], *(bf16x8*)&bzh[tt][ks], acc, 0, 0, 0);
#pragma unroll
            for (int ks = 0; ks < 4; ++ks)
                acc = __builtin_amdgcn_mfma_f32_32x32x16_bf16(al[ks], *(bf16x8*)&bzh[tt][ks], acc, 0, 0, 0);
#pragma unroll
            for (int ks = 0; ks < 4; ++ks)
                acc = __builtin_amdgcn_mfma_f32_32x32x16_bf16(ah[ks], *(bf16x8*)&bzl[tt][ks], acc, 0, 0, 0);
            float m = acc[0];
#pragma unroll
            for (int r = 1; r < 16; ++r) m = fmaxf(m, acc[r]);
            float rm = fmaxf(tt == 0 ? runm[0] : runm[1], m);
            if (tt == 0) runm[0] = rm; else runm[1] = rm;
            float thr = rm - (tt == 0 ? gapd[0] : gapd[1]);
            unsigned bits = 0;
#pragma unroll
            for (int r = 0; r < 16; ++r)
                bits |= (acc[r] >= thr) ? (1u << r) : 0u;
            unsigned sh = bits << ((ct & 1) * 16);
            if (tt == 0) mask0[ct >> 1] |= sh; else mask1[ct >> 1] |= sh;
        }
    }

    // ---- exchange halves: owner lane l owns in-wave token l (ttile=half) ----
    unsigned om[8], xm[8];
#pragma unroll
    for (int i = 0; i < 8; ++i) {
        om[i] = half ? mask1[i] : mask0[i];
        xm[i] = __shfl_xor(half ? mask0[i] : mask1[i], 32);
    }

    // ---- phase B: exact reload + re-rank (textually R2) ----
    const int hwme = base + tid;
    float z[DIM];
    float sumz;
    {
#pragma clang fp contract(off)
        sumz = 0.f;
#pragma unroll
        for (int d = 0; d < DIM; ++d) {
            float v = zb[(size_t)d * HW + hwme];
            z[d] = v;
            float p = v * v;
            sumz = sumz + p;
        }
    }

    float best = 3.402823466e38f;
    int bk = 0;
    for (int ct = 0; ct < 16; ++ct) {
        unsigned A = (om[ct >> 1] >> ((ct & 1) * 16)) & 0xFFFFu;
        unsigned B = (xm[ct >> 1] >> ((ct & 1) * 16)) & 0xFFFFu;
        // deposit: bit r -> kk = (r&3) + 4*h_src + 8*(r>>2)
        unsigned wo = ((A & 0xFu)) | (((A >> 4) & 0xFu) << 8) |
                      (((A >> 8) & 0xFu) << 16) | (((A >> 12) & 0xFu) << 24);
        unsigned wx = ((B & 0xFu)) | (((B >> 4) & 0xFu) << 8) |
                      (((B >> 8) & 0xFu) << 16) | (((B >> 12) & 0xFu) << 24);
        unsigned wc = half ? ((wo << 4) | wx) : (wo | (wx << 4));
        while (wc) {
            int kk = __builtin_ctz(wc);
            wc &= wc - 1;
            int k = 32 * ct + kk;
            const float4* c4 = (const float4*)(cb + (size_t)k * DIM);
            float a0 = 0.f;
#pragma unroll
            for (int g = 0; g < DIM / 4; ++g) {
                float4 u = c4[g];
                a0 = fmaf(z[4 * g + 0], u.x, a0);
                a0 = fmaf(z[4 * g + 1], u.y, a0);
                a0 = fmaf(z[4 * g + 2], u.z, a0);
                a0 = fmaf(z[4 * g + 3], u.w, a0);
            }
            float d2 = (sumz - 2.0f * a0) + sumc_s[k];
            if (d2 < best) { best = d2; bk = k; }
        }
    }

    // ---- epilogue (textually R2) ----
    inds_out[(size_t)gid * TOKBLK + tid] = (float)bk;
    float* ob = out + (size_t)b * DIM * HW;
    float lsum = 0.f;
    const float4* q4 = (const float4*)(cb + (size_t)bk * DIM);
    {
#pragma clang fp contract(off)
#pragma unroll
        for (int g = 0; g < DIM / 4; ++g) {
            float4 qq = q4[g];
            float qv[4] = {qq.x, qq.y, qq.z, qq.w};
#pragma unroll
            for (int j = 0; j < 4; ++j) {
                int d = g * 4 + j;
                float t1 = qv[j] - z[d];               // fl(z_q - z)
                ob[(size_t)d * HW + hwme] = z[d] + t1; // fl(z + fl(z_q - z))
                float p = t1 * t1;
                lsum = lsum + p;
            }
        }
    }

    // ---- two 256-leaf trees (R2's exact association) ----
    __syncthreads();
    red_s[tid] = lsum;
    __syncthreads();
#pragma unroll
    for (int s = 128; s > 0; s >>= 1) {
        if ((tid & 255) < s) red_s[tid] = red_s[tid] + red_s[tid + s];
        __syncthreads();
    }
    if (tid == 0)   loss_part[2 * gid]     = red_s[0];
    if (tid == 256) loss_part[2 * gid + 1] = red_s[256];

    // ---- fused final reduce: last-done block sums 16 partials/batch ----
    __syncthreads();
    if (tid == 0) {
        __threadfence();                                   // publish partials
        int prev = atomicAdd((int*)(ws + WS_CNT), 1);      // device-scope
        last_s = (prev == BLOCKS - 1) ? 1 : 0;
    }
    __syncthreads();
    if (last_s && tid < NB) {
        __threadfence();   // order our reads after all published partials
        float s = 0.f;
        for (int i = 0; i < 16; ++i)
            s = s + loss_part[tid * 16 + i];               // fixed order == R2
        float m = s * (1.0f / (HW * DIM));                 // exact /2^18
        loss_out[tid] = m + 0.25f * m;
    }
}

extern "C" void kernel_launch(void* const* d_in, const int* in_sizes, int n_in,
                              void* d_out, int out_size, void* d_ws, size_t ws_size,
                              hipStream_t stream)
{
    const float* z_e = (const float*)d_in[0];
    const float* cb  = (const float*)d_in[1];

    float* out  = (float*)d_out;
    float* loss = out + (size_t)NB * DIM * HW;  // 8388608
    float* inds = loss + NB;                    // 8388640
    float* ws   = (float*)d_ws;

    vq_prep<<<8, 64, 0, stream>>>(cb, ws);
    vq_main<<<BLOCKS, TPB, 0, stream>>>(z_e, cb, ws, out, ws + WS_PART, inds, loss);
}

// Round 27
// 82.965 us; speedup vs baseline: 1.0648x; 1.0648x over previous
//
#include <hip/hip_runtime.h>

#define NEMB 512
#define DIM 64
#define NB 32
#define HW 4096
#define NTOK (NB * HW)            // 131072
#define TPB 512                   // 8 waves
#define TOKBLK 512                // tokens per block
#define BLOCKS (NTOK / TOKBLK)    // 256

typedef float f32x16 __attribute__((ext_vector_type(16)));
typedef short bf16x8 __attribute__((ext_vector_type(8)));

// ws float-offsets
#define WS_PART 0                 // [512] loss partials
#define WS_SUMC 512               // [512] exact row norms
#define WS_CMAXP 1024             // [8] per-prep-block cmax partials
#define WS_SCMAXP 1032            // [8] per-prep-block scmax partials
#define WS_CH 1040                // u32[512*32] packed bf16-hi (16B aligned)
#define WS_CL (1040 + 16384)      // u32[512*32] packed bf16-lo

// RNE float->bf16 (self-contained, deterministic; inputs finite)
__device__ __forceinline__ unsigned short f2bf(float f) {
    unsigned u = __float_as_uint(f);
    unsigned r = u + 0x7FFFu + ((u >> 16) & 1u);
    return (unsigned short)(r >> 16);
}
__device__ __forceinline__ float bf2f(unsigned short h) {
    return __uint_as_float((unsigned)h << 16);
}

// prep: PARALLEL (8 blocks x 64). Row k: exact sumc (R2 order) + bf16 hi/lo
// split (packed) + per-block cmax/scmax partials (wave shuffle-reduce).
__global__ void vq_prep(const float* __restrict__ cb, float* __restrict__ ws)
{
    const int tid = threadIdx.x;              // 0..63 (one wave)
    const int k   = blockIdx.x * 64 + tid;    // 0..511

    float sc_v;
    {   // exact sumc: rounded squares, sequential adds (bit-exact R2)
#pragma clang fp contract(off)
        float s = 0.f;
#pragma unroll
        for (int d = 0; d < DIM; ++d) {
            float v = cb[k * DIM + d];
            float p = v * v;
            s = s + p;
        }
        sc_v = s;
        ws[WS_SUMC + k] = s;
    }

    float cmax_t = 0.f;
    unsigned* chp = (unsigned*)(ws + WS_CH) + k * 32;
    unsigned* clp = (unsigned*)(ws + WS_CL) + k * 32;
#pragma unroll
    for (int q = 0; q < 32; ++q) {
        float v0 = cb[k * DIM + 2 * q], v1 = cb[k * DIM + 2 * q + 1];
        cmax_t = fmaxf(cmax_t, fmaxf(fabsf(v0), fabsf(v1)));
        unsigned short h0 = f2bf(v0), h1 = f2bf(v1);
        unsigned short l0 = f2bf(v0 - bf2f(h0)), l1 = f2bf(v1 - bf2f(h1));
        chp[q] = (unsigned)h0 | ((unsigned)h1 << 16);
        clp[q] = (unsigned)l0 | ((unsigned)l1 << 16);
    }

    // wave-wide fmax reduce (order-independent => deterministic)
    float cm = cmax_t, sm = sc_v;
#pragma unroll
    for (int off = 32; off; off >>= 1) {
        cm = fmaxf(cm, __shfl_xor(cm, off));
        sm = fmaxf(sm, __shfl_xor(sm, off));
    }
    if (tid == 0) {
        ws[WS_CMAXP  + blockIdx.x] = cm;
        ws[WS_SCMAXP + blockIdx.x] = sm;
    }
}

// main: MFMA bf16-split filter (A=codes, B=tokens) + exact fp32 re-rank.
// == R10's measured-74us kernel, except sc2 staging maxes 8 partials.
__global__ __launch_bounds__(TPB, 2)
void vq_main(const float* __restrict__ z_e, const float* __restrict__ cb,
             const float* __restrict__ ws, float* __restrict__ out,
             float* __restrict__ loss_part, float* __restrict__ inds_out)
{
    __shared__ uint4 ch_s[NEMB * 9];   // 72 KB, rotation-swizzled blocks
    __shared__ uint4 cl_s[NEMB * 9];   // 72 KB
    __shared__ float sumc_s[NEMB];     // 2 KB
    __shared__ float red_s[TPB];       // 2 KB
    __shared__ float sc2[2];

    const int tid  = threadIdx.x;
    const int gid  = blockIdx.x;
    const int b    = gid >> 3;
    const int base = (gid & 7) * TOKBLK;
    const int w    = tid >> 6;
    const int l    = tid & 63;
    const int col  = l & 31;
    const int half = l >> 5;

    // ---- stage swizzled bf16 codebook + sumc ----
    {
        const uint4* chg = (const uint4*)(ws + WS_CH);
        const uint4* clg = (const uint4*)(ws + WS_CL);
#pragma unroll
        for (int i = 0; i < 8; ++i) {
            int idx = i * TPB + tid;          // 0..4095
            int c = idx >> 3, bd = idx & 7;
            int slot = (bd + c) & 7;          // rotation swizzle (~2-way banks)
            ch_s[c * 9 + slot] = chg[idx];
            cl_s[c * 9 + slot] = clg[idx];
        }
        sumc_s[tid] = ws[WS_SUMC + tid];
        if (tid == 0) {
            float cm = ws[WS_CMAXP], sm = ws[WS_SCMAXP];
#pragma unroll
            for (int i = 1; i < 8; ++i) {
                cm = fmaxf(cm, ws[WS_CMAXP + i]);
                sm = fmaxf(sm, ws[WS_SCMAXP + i]);
            }
            sc2[0] = cm; sc2[1] = sm;
        }
    }

    // ---- z B-frags (bf16 hi/lo) + L1z / approx sumz ----
    const float* zb = z_e + (size_t)b * DIM * HW;
    const int t0 = base + w * 64;
    uint4 bzh[2][4], bzl[2][4];
    float l1p[2] = {0.f, 0.f}, szp[2] = {0.f, 0.f};
#pragma unroll
    for (int tt = 0; tt < 2; ++tt) {
        int tok = t0 + tt * 32 + col;
#pragma unroll
        for (int ks = 0; ks < 4; ++ks) {
            unsigned hh[8], ll[8];
#pragma unroll
            for (int j = 0; j < 8; ++j) {
                int d = 16 * ks + 8 * half + j;
                float v = zb[(size_t)d * HW + tok];
                l1p[tt] += fabsf(v);
                szp[tt] = fmaf(v, v, szp[tt]);
                unsigned short h = f2bf(v);
                unsigned short lo = f2bf(v - bf2f(h));
                hh[j] = h; ll[j] = lo;
            }
            bzh[tt][ks] = make_uint4(hh[0] | (hh[1] << 16), hh[2] | (hh[3] << 16),
                                     hh[4] | (hh[5] << 16), hh[6] | (hh[7] << 16));
            bzl[tt][ks] = make_uint4(ll[0] | (ll[1] << 16), ll[2] | (ll[3] << 16),
                                     ll[4] | (ll[5] << 16), ll[6] | (ll[7] << 16));
        }
    }
    float L1[2], SZ[2];
#pragma unroll
    for (int tt = 0; tt < 2; ++tt) {
        L1[tt] = l1p[tt] + __shfl_xor(l1p[tt], 32);
        SZ[tt] = szp[tt] + __shfl_xor(szp[tt], 32);
    }
    __syncthreads();

    const float cmax = sc2[0], scmax = sc2[1];
    float gapd[2];
#pragma unroll
    for (int tt = 0; tt < 2; ++tt)
        gapd[tt] = 1.2e-4f * cmax * L1[tt] + 0.5f * scmax + 1.2e-7f * SZ[tt] + 1e-6f;

    // ---- MFMA filter: D[code][token], 3 split passes ----
    unsigned mask0[8], mask1[8];
#pragma unroll
    for (int i = 0; i < 8; ++i) { mask0[i] = 0u; mask1[i] = 0u; }
    float runm[2] = {-3.402823466e38f, -3.402823466e38f};

    for (int ct = 0; ct < 16; ++ct) {
        bf16x8 ah[4], al[4];
        const int c = 32 * ct + col;
        const int rowb = c * 9;
#pragma unroll
        for (int ks = 0; ks < 4; ++ks) {
            int slot = ((2 * ks + half) + c) & 7;
            uint4 u1 = ch_s[rowb + slot];
            uint4 u2 = cl_s[rowb + slot];
            ah[ks] = *(bf16x8*)&u1;
            al[ks] = *(bf16x8*)&u2;
        }
#pragma unroll
        for (int tt = 0; tt < 2; ++tt) {
            f32x16 acc = {0.f, 0.f, 0.f, 0.f, 0.f, 0.f, 0.f, 0.f,
                          0.f, 0.f, 0.f, 0.f, 0.f, 0.f, 0.f, 0.f};
#pragma unroll
            for (int ks = 0; ks < 4; ++ks)
                acc = __builtin_amdgcn_mfma_f32_32x32x16_bf16(ah[ks], *(bf16x8*)&bzh[tt][ks], acc, 0, 0, 0);
#pragma unroll
            for (int ks = 0; ks < 4; ++ks)
                acc = __builtin_amdgcn_mfma_f32_32x32x16_bf16(al[ks], *(bf16x8*)&bzh[tt][ks], acc, 0, 0, 0);
#pragma unroll
            for (int ks = 0; ks < 4; ++ks)
                acc = __builtin_amdgcn_mfma_f32_32x32x16_bf16(ah[ks], *(bf16x8*)&bzl[tt][ks], acc, 0, 0, 0);
            float m = acc[0];
#pragma unroll
            for (int r = 1; r < 16; ++r) m = fmaxf(m, acc[r]);
            float rm = fmaxf(tt == 0 ? runm[0] : runm[1], m);
            if (tt == 0) runm[0] = rm; else runm[1] = rm;
            float thr = rm - (tt == 0 ? gapd[0] : gapd[1]);
            unsigned bits = 0;
#pragma unroll
            for (int r = 0; r < 16; ++r)
                bits |= (acc[r] >= thr) ? (1u << r) : 0u;
            unsigned sh = bits << ((ct & 1) * 16);
            if (tt == 0) mask0[ct >> 1] |= sh; else mask1[ct >> 1] |= sh;
        }
    }

    // ---- exchange halves: owner lane l owns in-wave token l (ttile=half) ----
    unsigned om[8], xm[8];
#pragma unroll
    for (int i = 0; i < 8; ++i) {
        om[i] = half ? mask1[i] : mask0[i];
        xm[i] = __shfl_xor(half ? mask0[i] : mask1[i], 32);
    }

    // ---- phase B: exact reload + re-rank (textually R2) ----
    const int hwme = base + tid;
    float z[DIM];
    float sumz;
    {
#pragma clang fp contract(off)
        sumz = 0.f;
#pragma unroll
        for (int d = 0; d < DIM; ++d) {
            float v = zb[(size_t)d * HW + hwme];
            z[d] = v;
            float p = v * v;
            sumz = sumz + p;
        }
    }

    float best = 3.402823466e38f;
    int bk = 0;
    for (int ct = 0; ct < 16; ++ct) {
        unsigned A = (om[ct >> 1] >> ((ct & 1) * 16)) & 0xFFFFu;
        unsigned B = (xm[ct >> 1] >> ((ct & 1) * 16)) & 0xFFFFu;
        // deposit: bit r -> kk = (r&3) + 4*h_src + 8*(r>>2)
        unsigned wo = ((A & 0xFu)) | (((A >> 4) & 0xFu) << 8) |
                      (((A >> 8) & 0xFu) << 16) | (((A >> 12) & 0xFu) << 24);
        unsigned wx = ((B & 0xFu)) | (((B >> 4) & 0xFu) << 8) |
                      (((B >> 8) & 0xFu) << 16) | (((B >> 12) & 0xFu) << 24);
        unsigned wc = half ? ((wo << 4) | wx) : (wo | (wx << 4));
        while (wc) {
            int kk = __builtin_ctz(wc);
            wc &= wc - 1;
            int k = 32 * ct + kk;
            const float4* c4 = (const float4*)(cb + (size_t)k * DIM);
            float a0 = 0.f;
#pragma unroll
            for (int g = 0; g < DIM / 4; ++g) {
                float4 u = c4[g];
                a0 = fmaf(z[4 * g + 0], u.x, a0);
                a0 = fmaf(z[4 * g + 1], u.y, a0);
                a0 = fmaf(z[4 * g + 2], u.z, a0);
                a0 = fmaf(z[4 * g + 3], u.w, a0);
            }
            float d2 = (sumz - 2.0f * a0) + sumc_s[k];
            if (d2 < best) { best = d2; bk = k; }
        }
    }

    // ---- epilogue (textually R2) ----
    inds_out[(size_t)gid * TOKBLK + tid] = (float)bk;
    float* ob = out + (size_t)b * DIM * HW;
    float lsum = 0.f;
    const float4* q4 = (const float4*)(cb + (size_t)bk * DIM);
    {
#pragma clang fp contract(off)
#pragma unroll
        for (int g = 0; g < DIM / 4; ++g) {
            float4 qq = q4[g];
            float qv[4] = {qq.x, qq.y, qq.z, qq.w};
#pragma unroll
            for (int j = 0; j < 4; ++j) {
                int d = g * 4 + j;
                float t1 = qv[j] - z[d];               // fl(z_q - z)
                ob[(size_t)d * HW + hwme] = z[d] + t1; // fl(z + fl(z_q - z))
                float p = t1 * t1;
                lsum = lsum + p;
            }
        }
    }

    // ---- two 256-leaf trees (R2's exact association) ----
    __syncthreads();
    red_s[tid] = lsum;
    __syncthreads();
#pragma unroll
    for (int s = 128; s > 0; s >>= 1) {
        if ((tid & 255) < s) red_s[tid] = red_s[tid] + red_s[tid + s];
        __syncthreads();
    }
    if (tid == 0)   loss_part[2 * gid]     = red_s[0];
    if (tid == 256) loss_part[2 * gid + 1] = red_s[256];
}

// deterministic final reduce: 16 partials per batch, fixed order (== R2)
__global__ void vq_loss_final(const float* __restrict__ part,
                              float* __restrict__ loss_out)
{
    int b = threadIdx.x;
    if (b < NB) {
        float s = 0.f;
        for (int i = 0; i < 16; ++i)
            s = s + part[b * 16 + i];
        float m = s * (1.0f / (HW * DIM));   // exact /2^18
        loss_out[b] = m + 0.25f * m;
    }
}

extern "C" void kernel_launch(void* const* d_in, const int* in_sizes, int n_in,
                              void* d_out, int out_size, void* d_ws, size_t ws_size,
                              hipStream_t stream)
{
    const float* z_e = (const float*)d_in[0];
    const float* cb  = (const float*)d_in[1];

    float* out  = (float*)d_out;
    float* loss = out + (size_t)NB * DIM * HW;  // 8388608
    float* inds = loss + NB;                    // 8388640
    float* ws   = (float*)d_ws;

    vq_prep<<<8, 64, 0, stream>>>(cb, ws);
    vq_main<<<BLOCKS, TPB, 0, stream>>>(z_e, cb, ws, out, ws + WS_PART, inds);
    vq_loss_final<<<1, 64, 0, stream>>>(ws + WS_PART, loss);
}